// Round 3
// baseline (74.900 us; speedup 1.0000x reference)
//
#include <hip/hip_runtime.h>
#include <math.h>

#define BLOCK 256
#define NPB 512        // samples per block (4 N-slices instead of 16)
#define NPAIRS (NPB/2) // 256 packed sample pairs

#if __has_builtin(__builtin_amdgcn_exp2f)
#define EXP2F(x) __builtin_amdgcn_exp2f(x)
#else
#define EXP2F(x) exp2f(x)
#endif

typedef float v2f __attribute__((ext_vector_type(2)));
typedef float v4f __attribute__((ext_vector_type(4)));

// out[b,m] = coefN * sum_n exp2(a_n*px + b_n*py - c_n - q_m)
//   a = 2t*sx, b = 2t*sy, c = t*|s|^2, q_m = t*|p_m|^2  (arg always <= 0)
//
// R13 == R12 resubmitted (R12's bench was an infra failure: "container
// failed twice", no compile/correctness signal). Theory unchanged:
// R11 halved LDS+issue work per exp and moved NOTHING (72.33 -> 72.36),
// so the kernel is not LDS/issue-bound. The R10/R11 invariant was 1M
// atomicAdds with 16 N-slice writers contending per out[b,m] address; a
// contended-L2-RMW model predicts the sticky ~30us beyond the 40.6us
// harness fill. This round: NPB=512, grid (4,128)=512 blocks, BLOCK=256,
// 2 m/thread. Atomics 1M -> 256K, writers/address 16 -> 4. Occupancy
// 2 waves/SIMD; per-iter 4 indep exps, unroll 4 -> 16 in flight.
__global__ __launch_bounds__(BLOCK) void kde_kernel(
    const float* __restrict__ inputs,   // (B, N, 2)
    const float* __restrict__ points,   // (M, 2)
    float* __restrict__ out,            // (B, M), pre-zeroed
    int N, int M, float t, float t2, float coefN)
{
    const int b   = blockIdx.y;
    const int n0  = blockIdx.x * NPB;
    const int tid = (int)threadIdx.x;

    __shared__ v4f SAB[NPAIRS];         // {a0,a1,b0,b1} per sample pair (4 KB)
    __shared__ v2f SC[NPAIRS];          // {c0,c1} (2 KB)

    // every thread stages one sample pair: (sx0, sy0, sx1, sy1)
    if (n0 + 2 * tid + 1 < N) {
        const float4 s2 =
            reinterpret_cast<const float4*>(inputs)[((b * N + n0) >> 1) + tid];
        SAB[tid] = (v4f){t2 * s2.x, t2 * s2.z, t2 * s2.y, t2 * s2.w};
        SC[tid]  = (v2f){t * fmaf(s2.x, s2.x, s2.y * s2.y),
                         t * fmaf(s2.z, s2.z, s2.w * s2.w)};
    } else {
        // pad: zero-weight samples (exp2(-inf) = 0 contribution). -1e30f in
        // c makes the argument hugely negative regardless of p.
        SAB[tid] = (v4f){0.f, 0.f, 0.f, 0.f};
        SC[tid]  = (v2f){1e30f, 1e30f};
    }

    const int m0 = tid;
    const int m1 = tid + BLOCK;
    const float2* pts = reinterpret_cast<const float2*>(points);
    const float2 p0 = pts[m0 < M ? m0 : 0];
    const float2 p1 = pts[m1 < M ? m1 : 0];
    const float q0 = t * fmaf(p0.x, p0.x, p0.y * p0.y);
    const float q1 = t * fmaf(p1.x, p1.x, p1.y * p1.y);

    const v2f PX0 = {p0.x, p0.x}, PY0 = {p0.y, p0.y}, NQ0 = {-q0, -q0};
    const v2f PX1 = {p1.x, p1.x}, PY1 = {p1.y, p1.y}, NQ1 = {-q1, -q1};

    __syncthreads();

    v2f acc0 = {0.f, 0.f}, acc1 = {0.f, 0.f};

#pragma unroll 4
    for (int j = 0; j < NPAIRS; ++j) {
        const v4f ab = SAB[j];          // ds_read_b128 (broadcast)
        const v2f c  = SC[j];           // ds_read_b64
        const v2f a  = {ab.x, ab.y};
        const v2f bb = {ab.z, ab.w};
        const v2f k0 = NQ0 - c;         // v_pk_add (neg modifier)
        const v2f k1 = NQ1 - c;
        const v2f w0 = __builtin_elementwise_fma(a, PX0,
                           __builtin_elementwise_fma(bb, PY0, k0));
        const v2f w1 = __builtin_elementwise_fma(a, PX1,
                           __builtin_elementwise_fma(bb, PY1, k1));
        v2f e0, e1;
        e0.x = EXP2F(w0.x); e0.y = EXP2F(w0.y);
        e1.x = EXP2F(w1.x); e1.y = EXP2F(w1.y);
        acc0 += e0;                     // v_pk_add_f32
        acc1 += e1;
    }

    if (m0 < M) atomicAdd(&out[(size_t)b * M + m0], (acc0.x + acc0.y) * coefN);
    if (m1 < M) atomicAdd(&out[(size_t)b * M + m1], (acc1.x + acc1.y) * coefN);
}

extern "C" void kernel_launch(void* const* d_in, const int* in_sizes, int n_in,
                              void* d_out, int out_size, void* d_ws, size_t ws_size,
                              hipStream_t stream) {
    const float* inputs = (const float*)d_in[0];   // (B, N, 2) fp32
    const float* points = (const float*)d_in[1];   // (M, 2) fp32
    float* out = (float*)d_out;                    // (B, M) fp32

    const int M = in_sizes[1] / 2;          // 512
    const int B = out_size / M;             // 128
    const int N = in_sizes[0] / (2 * B);    // 2048

    // Silverman bandwidth, d = 2
    const double h    = pow(4.0 / 4.0, 1.0 / 6.0) * pow((double)N, -1.0 / 6.0);
    const double h2   = h * h;
    const double coef = 1.0 / (2.0 * M_PI * h2);
    const double td   = 0.5 / (h2 * M_LN2);       // exp(-0.5*sq/h^2) = exp2(-t*sq)
    const float  t     = (float)td;
    const float  t2    = (float)(2.0 * td);
    const float  coefN = (float)(coef / (double)N);

    hipMemsetAsync(out, 0, (size_t)out_size * sizeof(float), stream);

    dim3 grid((N + NPB - 1) / NPB, B);      // (4, 128) = 512 blocks
    kde_kernel<<<grid, BLOCK, 0, stream>>>(inputs, points, out,
                                           N, M, t, t2, coefN);
}

// Round 4
// 72.715 us; speedup vs baseline: 1.0301x; 1.0301x over previous
//
#include <hip/hip_runtime.h>
#include <math.h>

#define BLOCK 256
#define NPB 128        // samples per block
#define NPAIRS (NPB/2) // 64 packed sample pairs

#if __has_builtin(__builtin_amdgcn_exp2f)
#define EXP2F(x) __builtin_amdgcn_exp2f(x)
#else
#define EXP2F(x) exp2f(x)
#endif

typedef float v2f __attribute__((ext_vector_type(2)));
typedef float v4f __attribute__((ext_vector_type(4)));

// out[b,m] = coefN * sum_n exp2(a_n*px + b_n*py - c_n - q_m)
//   a = 2t*sx, b = 2t*sy, c = t*|s|^2, q_m = t*|p_m|^2  (arg always <= 0)
//
// R14: REVERT to the best-measured configuration (72.33 us).
// Session evidence: R11 halved LDS+issue work per exp (72.36), R13 cut
// atomics and contention 4x (74.90) -- every structural change lands within
// 72.3-74.9. Issue-model arithmetic puts the compute loop at ~9-12 us, so
// dur_us decomposes as ~40.5us harness poison-fill (83% HBM peak, its own
// roofline) + ~20us fixed harness small-dispatch overhead + ~10us kernel.
// Remaining kernel-side headroom (~2-3us) is below the ~2.5us noise band.
// This round restores the proven optimum; expected 72.3 +/- 1.5.
__global__ __launch_bounds__(BLOCK) void kde_kernel(
    const float* __restrict__ inputs,   // (B, N, 2)
    const float* __restrict__ points,   // (M, 2)
    float* __restrict__ out,            // (B, M), pre-zeroed
    int N, int M, float t, float t2, float coefN)
{
    const int b   = blockIdx.y;
    const int n0  = blockIdx.x * NPB;
    const int tid = (int)threadIdx.x;

    __shared__ v4f SAB[NPAIRS];         // {a0,a1,b0,b1} per sample pair (1 KB)
    __shared__ v2f SC[NPAIRS];          // {c0,c1} (512 B)

    if (tid < NPAIRS) {
        // two consecutive samples: (sx0, sy0, sx1, sy1)
        const float4 s2 =
            reinterpret_cast<const float4*>(inputs)[((b * N + n0) >> 1) + tid];
        SAB[tid] = (v4f){t2 * s2.x, t2 * s2.z, t2 * s2.y, t2 * s2.w};
        SC[tid]  = (v2f){t * fmaf(s2.x, s2.x, s2.y * s2.y),
                         t * fmaf(s2.z, s2.z, s2.w * s2.w)};
    }

    const int m0 = tid;
    const int m1 = tid + BLOCK;
    const float2* pts = reinterpret_cast<const float2*>(points);
    const float2 p0 = pts[m0 < M ? m0 : 0];
    const float2 p1 = pts[m1 < M ? m1 : 0];
    const float q0 = t * fmaf(p0.x, p0.x, p0.y * p0.y);
    const float q1 = t * fmaf(p1.x, p1.x, p1.y * p1.y);

    const v2f PX0 = {p0.x, p0.x}, PY0 = {p0.y, p0.y}, NQ0 = {-q0, -q0};
    const v2f PX1 = {p1.x, p1.x}, PY1 = {p1.y, p1.y}, NQ1 = {-q1, -q1};

    __syncthreads();

    v2f acc0 = {0.f, 0.f}, acc1 = {0.f, 0.f};

#pragma unroll 4
    for (int j = 0; j < NPAIRS; ++j) {
        const v4f ab = SAB[j];          // ds_read_b128 (broadcast)
        const v2f c  = SC[j];           // ds_read_b64
        const v2f a  = {ab.x, ab.y};
        const v2f bb = {ab.z, ab.w};
        const v2f k0 = NQ0 - c;         // v_pk_add (neg modifier)
        const v2f k1 = NQ1 - c;
        const v2f w0 = __builtin_elementwise_fma(a, PX0,
                           __builtin_elementwise_fma(bb, PY0, k0));
        const v2f w1 = __builtin_elementwise_fma(a, PX1,
                           __builtin_elementwise_fma(bb, PY1, k1));
        v2f e0, e1;
        e0.x = EXP2F(w0.x); e0.y = EXP2F(w0.y);
        e1.x = EXP2F(w1.x); e1.y = EXP2F(w1.y);
        acc0 += e0;                     // v_pk_add_f32
        acc1 += e1;
    }

    if (m0 < M) atomicAdd(&out[(size_t)b * M + m0], (acc0.x + acc0.y) * coefN);
    if (m1 < M) atomicAdd(&out[(size_t)b * M + m1], (acc1.x + acc1.y) * coefN);
}

extern "C" void kernel_launch(void* const* d_in, const int* in_sizes, int n_in,
                              void* d_out, int out_size, void* d_ws, size_t ws_size,
                              hipStream_t stream) {
    const float* inputs = (const float*)d_in[0];   // (B, N, 2) fp32
    const float* points = (const float*)d_in[1];   // (M, 2) fp32
    float* out = (float*)d_out;                    // (B, M) fp32

    const int M = in_sizes[1] / 2;          // 512
    const int B = out_size / M;             // 128
    const int N = in_sizes[0] / (2 * B);    // 2048

    // Silverman bandwidth, d = 2
    const double h    = pow(4.0 / 4.0, 1.0 / 6.0) * pow((double)N, -1.0 / 6.0);
    const double h2   = h * h;
    const double coef = 1.0 / (2.0 * M_PI * h2);
    const double td   = 0.5 / (h2 * M_LN2);       // exp(-0.5*sq/h^2) = exp2(-t*sq)
    const float  t     = (float)td;
    const float  t2    = (float)(2.0 * td);
    const float  coefN = (float)(coef / (double)N);

    hipMemsetAsync(out, 0, (size_t)out_size * sizeof(float), stream);

    dim3 grid(N / NPB, B);                  // (16, 128) = 2048 blocks
    kde_kernel<<<grid, BLOCK, 0, stream>>>(inputs, points, out,
                                           N, M, t, t2, coefN);
}